// Round 5
// baseline (399.422 us; speedup 1.0000x reference)
//
#include <hip/hip_runtime.h>

#define D_MODEL 2048
#define S_LEN 2048
#define HQ 16
#define HKV 4
#define DH 128
#define QKV_W 3072
#define M_TOK 8192

typedef unsigned short u16;
typedef __bf16 bf16x8 __attribute__((ext_vector_type(8)));
typedef float f32x4 __attribute__((ext_vector_type(4)));
typedef float f32x16 __attribute__((ext_vector_type(16)));

__device__ __forceinline__ u16 f2bf(float f) {
  union { float f; unsigned u; } v; v.f = f;
  unsigned u = v.u;
  return (u16)((u + 0x7fffu + ((u >> 16) & 1u)) >> 16);
}

__device__ __forceinline__ bf16x8 ld_frag(const u16* p) {
  bf16x8 r; __builtin_memcpy(&r, p, 16); return r;
}

__device__ __forceinline__ void gl_lds16(const u16* g, u16* l) {
  __builtin_amdgcn_global_load_lds(
      (const __attribute__((address_space(1))) void*)g,
      (__attribute__((address_space(3))) void*)l, 16, 0, 0);
}

__device__ __forceinline__ unsigned cvtpk(float lo, float hi_) {
  unsigned r;
  asm("v_cvt_pk_bf16_f32 %0, %1, %2" : "=v"(r) : "v"(lo), "v"(hi_));
  return r;
}

#define MFMA(a, b, c) __builtin_amdgcn_mfma_f32_16x16x32_bf16(a, b, c, 0, 0, 0)
#define MFMA32(a, b, c) __builtin_amdgcn_mfma_f32_32x32x16_bf16(a, b, c, 0, 0, 0)

__device__ __forceinline__ float vmax16(const f32x16& v) {
  float a = fmaxf(fmaxf(v[0], v[1]), fmaxf(v[2], v[3]));
  float b = fmaxf(fmaxf(v[4], v[5]), fmaxf(v[6], v[7]));
  float c = fmaxf(fmaxf(v[8], v[9]), fmaxf(v[10], v[11]));
  float d = fmaxf(fmaxf(v[12], v[13]), fmaxf(v[14], v[15]));
  return fmaxf(fmaxf(a, b), fmaxf(c, d));
}
__device__ __forceinline__ float vsum16(const f32x16& v) {
  float a = (v[0] + v[1]) + (v[2] + v[3]);
  float b = (v[4] + v[5]) + (v[6] + v[7]);
  float c = (v[8] + v[9]) + (v[10] + v[11]);
  float d = (v[12] + v[13]) + (v[14] + v[15]);
  return (a + b) + (c + d);
}

// ---------------- fp32 -> bf16 convert (optionally scale first scale_n) ----
__global__ __launch_bounds__(256) void k_f32_to_bf16(const float* __restrict__ s,
                                                     u16* __restrict__ d,
                                                     long scale_n) {
  long i = (long)(blockIdx.x * 256 + threadIdx.x) * 8;
  float sc = (i < scale_n) ? 0.08838834764831845f : 1.0f;
  float a[8];
  __builtin_memcpy(a, s + i, 32);
  u16 r[8];
#pragma unroll
  for (int j = 0; j < 8; ++j) r[j] = f2bf(a[j] * sc);
  __builtin_memcpy(d + i, r, 16);
}

// ---------------- 256x256 quad-buffered GEMM  C = A[M,K] * B[N,K]^T --------
// 8 waves (2Mx4N). BK=32, 4 LDS tile-buffers (128KB), prefetch 3 tiles ahead.
// Per tile: 2 phases x {ds_read(8|4) ; stage 2 gl_lds(t+3) ; bar ; lgkm0 ;
// setprio 16 MFMA ; [vmcnt(8) gate at tile end] ; bar}.  Gate drains tile
// t+1 (issued 2 tiles earlier); tiles t+2,t+3 stay in flight.
template <int OUT_BF16>
__global__ __launch_bounds__(512, 2) void k_gemm256(const u16* __restrict__ A,
                                                    const u16* __restrict__ B,
                                                    void* __restrict__ C,
                                                    int M, int N, int K) {
  __shared__ __attribute__((aligned(16))) u16 As[4][8192];  // 4 x 16KB
  __shared__ __attribute__((aligned(16))) u16 Bs[4][8192];
  const int tid = threadIdx.x;
  const int lane = tid & 63;
  const int wid = tid >> 6;
  const int l15 = lane & 15, l4 = lane >> 4;
  const int wr = wid >> 2, wc = wid & 3;  // 2x4 waves -> 128x64 out each

  const int swz = (blockIdx.x & 7) * (gridDim.x >> 3) + (blockIdx.x >> 3);
  const int mt = M >> 8;
  const long tm = (long)(swz % mt) * 256;
  const long tn = (long)(swz / mt) * 256;

  // T2 swizzle: stored chunk g = c ^ ((row>>1)&3); per-thread constant on
  // the read side since row = 16*frag + l15.
  const int cA = l4 ^ ((l15 >> 1) & 3);
  const int arow = wr * 128 + l15;
  const int brow = wc * 64 + l15;

  f32x4 acc[8][4] = {};
  bf16x8 af[4], bfr[4];

#define STG(dst, src, tbase, t_)                                          \
  do {                                                                    \
    _Pragma("unroll") for (int j = 0; j < 2; ++j) {                       \
      int p = tid + j * 512;                                              \
      int row = p >> 2, cc = p & 3;                                       \
      int g = cc ^ ((row >> 1) & 3);                                      \
      gl_lds16(src + (tbase + row) * (long)K + (long)(t_) * 32 + g * 8,   \
               (dst) + p * 8);                                            \
    }                                                                     \
  } while (0)

#define DSR_A(ptr, mh)                                                    \
  _Pragma("unroll") for (int m = 0; m < 4; ++m)                           \
      af[m] = ld_frag((ptr) + (arow + (mh) * 64 + m * 16) * 32 + cA * 8);
#define DSR_B(ptr)                                                        \
  _Pragma("unroll") for (int n = 0; n < 4; ++n)                           \
      bfr[n] = ld_frag((ptr) + (brow + n * 16) * 32 + cA * 8);
#define MM(mh)                                                            \
  _Pragma("unroll") for (int m = 0; m < 4; ++m)                           \
      _Pragma("unroll") for (int n = 0; n < 4; ++n)                       \
          acc[(mh) * 4 + m][n] = MFMA(af[m], bfr[n], acc[(mh) * 4 + m][n]);
#define LGKM0                                              \
  asm volatile("s_waitcnt lgkmcnt(0)" ::: "memory");       \
  __builtin_amdgcn_sched_barrier(0)

  const int NT = K >> 5;  // BK=32
  // prologue: stage tiles 0,1,2 (12 loads/thread); gate tile 0 (8 in flight)
  STG(&As[0][0], A, tm, 0); STG(&Bs[0][0], B, tn, 0);
  STG(&As[1][0], A, tm, 1); STG(&Bs[1][0], B, tn, 1);
  STG(&As[2][0], A, tm, 2); STG(&Bs[2][0], B, tn, 2);
  asm volatile("s_waitcnt vmcnt(8)" ::: "memory");
  __builtin_amdgcn_s_barrier();

  for (int t = 0; t < NT; ++t) {
    const u16* as_ = &As[t & 3][0];
    const u16* bs_ = &Bs[t & 3][0];
    u16* an_ = &As[(t + 3) & 3][0];
    u16* bn_ = &Bs[(t + 3) & 3][0];
    const bool st = (t + 3 < NT);

    // phase 0: A(mh0) + B reads, stage A(t+3)
    DSR_A(as_, 0);
    DSR_B(bs_);
    if (st) STG(an_, A, tm, t + 3);
    __builtin_amdgcn_s_barrier();
    LGKM0;
    __builtin_amdgcn_s_setprio(1); MM(0); __builtin_amdgcn_s_setprio(0);
    __builtin_amdgcn_s_barrier();

    // phase 1: A(mh1) reads (B reused), stage B(t+3)
    DSR_A(as_, 1);
    if (st) STG(bn_, B, tn, t + 3);
    __builtin_amdgcn_s_barrier();
    LGKM0;
    __builtin_amdgcn_s_setprio(1); MM(1); __builtin_amdgcn_s_setprio(0);
    // tile-boundary gate: drain tile t+1's 4 loads, keep t+2/t+3 in flight
    if (t + 3 < NT) {
      asm volatile("s_waitcnt vmcnt(8)" ::: "memory");
    } else if (t + 2 < NT) {
      asm volatile("s_waitcnt vmcnt(4)" ::: "memory");
    } else if (t + 1 < NT) {
      asm volatile("s_waitcnt vmcnt(0)" ::: "memory");
    }
    __builtin_amdgcn_s_barrier();
  }
#undef STG
#undef DSR_A
#undef DSR_B
#undef MM
#undef LGKM0

#pragma unroll
  for (int m = 0; m < 8; ++m)
#pragma unroll
    for (int n = 0; n < 4; ++n)
#pragma unroll
      for (int i = 0; i < 4; ++i) {
        long row = tm + wr * 128 + m * 16 + l4 * 4 + i;
        long col = tn + wc * 64 + n * 16 + l15;
        if (OUT_BF16)
          ((u16*)C)[row * N + col] = f2bf(acc[m][n][i]);
        else
          ((float*)C)[row * N + col] = acc[m][n][i];
      }
}

// ---------------- V transpose: qkv V-part [s,d] -> vt[b,kv][d][s] ----------
__global__ __launch_bounds__(256) void k_vtrans(const u16* __restrict__ qkv,
                                                u16* __restrict__ vt) {
  __shared__ u16 T[64][68];
  const int tid = threadIdx.x;
  const int st = blockIdx.x;
  const int dt = blockIdx.y;
  const int bh = blockIdx.z;
  const int b = bh >> 2, kvh = bh & 3;
  const long s0 = (long)st * 64, d0 = (long)dt * 64;
#pragma unroll
  for (int j = 0; j < 2; ++j) {
    int chunk = tid + j * 256;
    int row = chunk >> 3, c8 = chunk & 7;
    u16 tmp[8];
    __builtin_memcpy(tmp,
                     qkv + ((long)b * S_LEN + s0 + row) * QKV_W + 2560 +
                         kvh * DH + d0 + c8 * 8,
                     16);
    __builtin_memcpy(&T[row][c8 * 8], tmp, 16);
  }
  __syncthreads();
#pragma unroll
  for (int j = 0; j < 2; ++j) {
    int chunk = tid + j * 256;
    int drow = chunk >> 3, c8 = chunk & 7;
    u16 tmp[8];
#pragma unroll
    for (int e = 0; e < 8; ++e) tmp[e] = T[c8 * 8 + e][drow];
    __builtin_memcpy(vt + ((long)bh * DH + d0 + drow) * S_LEN + s0 + c8 * 8,
                     tmp, 16);
  }
}

// ---------------- flash attention, 8-wave 32x32 swapped-QK^T ---------------
__global__ __launch_bounds__(512, 2) void k_attn(const u16* __restrict__ qkv,
                                                 const u16* __restrict__ vt,
                                                 u16* __restrict__ ao) {
  __shared__ u16 Ks[2][64 * 128];
  __shared__ u16 Vs[2][128 * 64];
  const int tid = threadIdx.x;
  const int lane = tid & 63;
  const int wid = tid >> 6;
  const int l31 = lane & 31, hi = lane >> 5;
  const int qt = blockIdx.x & 7;
  const int hh = (blockIdx.x >> 3) & 3;
  const int bkv = blockIdx.x >> 5;
  const int b = bkv >> 2, kvh = bkv & 3;
  const int h = kvh * 4 + hh;
  const long rowbase = (long)b * S_LEN;
  const int q0 = qt * 256 + wid * 32;
  const long vbase = (long)bkv * DH * S_LEN;

  bf16x8 qf[8];
  {
    const u16* qrow = qkv + (rowbase + q0 + l31) * QKV_W + h * DH;
#pragma unroll
    for (int kk = 0; kk < 8; ++kk) qf[kk] = ld_frag(qrow + kk * 16 + hi * 8);
  }

  f32x16 o[4] = {};
  float m_run = -3.0e38f, l_run = 0.f;

#define STAGE(buf, tile)                                                      \
  do {                                                                        \
    long s0_ = (long)(tile) * 64;                                             \
    _Pragma("unroll") for (int j = 0; j < 2; ++j) {                           \
      int chunk = (wid * 2 + j) * 64 + lane;                                  \
      int row = chunk >> 4, cc = chunk & 15;                                  \
      gl_lds16(qkv + (rowbase + s0_ + row) * QKV_W + 2048 + kvh * DH +        \
                   ((cc ^ (row & 7)) * 8),                                    \
               &Ks[buf][chunk * 8]);                                          \
    }                                                                         \
    _Pragma("unroll") for (int j = 0; j < 2; ++j) {                           \
      int chunk = (wid * 2 + j) * 64 + lane;                                  \
      int row = chunk >> 3, cc = chunk & 7;                                   \
      gl_lds16(vt + vbase + (long)row * S_LEN + s0_ + ((cc ^ (row & 7)) * 8), \
               &Vs[buf][chunk * 8]);                                          \
    }                                                                         \
  } while (0)

  STAGE(0, 0);
  __syncthreads();

  int cur = 0;
  for (int kt = 0; kt < 32; ++kt) {
    if (kt + 1 < 32) STAGE(cur ^ 1, kt + 1);

    f32x16 p0 = {}, p1 = {};
    {
      const u16* ks = &Ks[cur][0];
      __builtin_amdgcn_s_setprio(1);
#pragma unroll
      for (int kk = 0; kk < 8; ++kk) {
        int ch0 = ((2 * kk + hi) ^ (l31 & 7));
        int ch1 = ((2 * kk + hi) ^ ((l31 + 32) & 7));
        bf16x8 kf0 = ld_frag(ks + l31 * 128 + ch0 * 8);
        bf16x8 kf1 = ld_frag(ks + (32 + l31) * 128 + ch1 * 8);
        p0 = MFMA32(kf0, qf[kk], p0);
        p1 = MFMA32(kf1, qf[kk], p1);
      }
      __builtin_amdgcn_s_setprio(0);
    }

    float mx = fmaxf(vmax16(p0), vmax16(p1));
    mx = fmaxf(mx, __shfl_xor(mx, 32, 64));
    bool need = (mx > m_run + 8.0f);
    if (__any(need)) {
      float nm = fmaxf(m_run, mx);
      float alpha = __expf(m_run - nm);
      m_run = nm;
      l_run *= alpha;
#pragma unroll
      for (int n2 = 0; n2 < 4; ++n2)
#pragma unroll
        for (int r = 0; r < 16; ++r) o[n2][r] *= alpha;
    }
#pragma unroll
    for (int r = 0; r < 16; ++r) {
      p0[r] = __expf(p0[r] - m_run);
      p1[r] = __expf(p1[r] - m_run);
    }
    float ts = vsum16(p0) + vsum16(p1);
    ts += __shfl_xor(ts, 32, 64);
    l_run += ts;

    {
      const u16* vs = &Vs[cur][0];
      __builtin_amdgcn_s_setprio(1);
#pragma unroll
      for (int ks_ = 0; ks_ < 4; ++ks_) {
        const f32x16& pp = (ks_ < 2) ? p0 : p1;
        const int bb = 8 * (ks_ & 1);
        unsigned A0 = cvtpk(pp[bb + 0], pp[bb + 1]);
        unsigned A1 = cvtpk(pp[bb + 2], pp[bb + 3]);
        unsigned B0 = cvtpk(pp[bb + 4], pp[bb + 5]);
        unsigned B1 = cvtpk(pp[bb + 6], pp[bb + 7]);
        asm volatile("v_permlane32_swap_b32 %0, %1" : "+v"(A0), "+v"(B0));
        asm volatile("v_permlane32_swap_b32 %0, %1" : "+v"(A1), "+v"(B1));
        union { unsigned u[4]; bf16x8 v; } pu;
        pu.u[0] = A0; pu.u[1] = A1; pu.u[2] = B0; pu.u[3] = B1;
#pragma unroll
        for (int n2 = 0; n2 < 4; ++n2) {
          int vr = n2 * 32 + l31;
          int ch = ((2 * ks_ + hi) ^ (vr & 7));
          bf16x8 vf = ld_frag(vs + vr * 64 + ch * 8);
          o[n2] = MFMA32(vf, pu.v, o[n2]);
        }
      }
      __builtin_amdgcn_s_setprio(0);
    }
    __syncthreads();
    cur ^= 1;
  }

  {
    float inv = 1.0f / l_run;
    u16* orow = ao + (rowbase + q0 + l31) * D_MODEL + h * DH;
#pragma unroll
    for (int n2 = 0; n2 < 4; ++n2)
#pragma unroll
      for (int g = 0; g < 4; ++g) {
        u16 tmp[4];
#pragma unroll
        for (int e = 0; e < 4; ++e) tmp[e] = f2bf(o[n2][g * 4 + e] * inv);
        __builtin_memcpy(orow + n2 * 32 + g * 8 + 4 * hi, tmp, 8);
      }
  }
#undef STAGE
}

// ---------------------------------------------------------------------------
extern "C" void kernel_launch(void* const* d_in, const int* in_sizes, int n_in,
                              void* d_out, int out_size, void* d_ws,
                              size_t ws_size, hipStream_t stream) {
  const float* x = (const float*)d_in[0];
  const float* wqkv = (const float*)d_in[2];
  const float* wo = (const float*)d_in[3];
  char* ws = (char*)d_ws;
  u16* xb = (u16*)(ws);                // 32MB (reused as ao later)
  u16* wqkvb = (u16*)(ws + 33554432);  // 12MB
  u16* wob = (u16*)(ws + 46137344);    // 8MB
  u16* qkv = (u16*)(ws + 54525952);    // 48MB
  u16* vt = (u16*)(ws + 104857600);    // 8MB
  u16* ao = xb;

  k_f32_to_bf16<<<8192, 256, 0, stream>>>(x, xb, 0);
  k_f32_to_bf16<<<3072, 256, 0, stream>>>(wqkv, wqkvb, 4194304L);
  k_f32_to_bf16<<<2048, 256, 0, stream>>>(wo, wob, 0);
  k_gemm256<1><<<384, 512, 0, stream>>>(xb, wqkvb, qkv, M_TOK, QKV_W, D_MODEL);
  k_vtrans<<<dim3(32, 2, 16), 256, 0, stream>>>(qkv, vt);
  k_attn<<<512, 512, 0, stream>>>(qkv, vt, ao);
  k_gemm256<0><<<256, 512, 0, stream>>>(ao, wob, d_out, M_TOK, D_MODEL,
                                        D_MODEL);
}

// Round 6
// 393.380 us; speedup vs baseline: 1.0154x; 1.0154x over previous
//
#include <hip/hip_runtime.h>

#define D_MODEL 2048
#define S_LEN 2048
#define HQ 16
#define HKV 4
#define DH 128
#define QKV_W 3072
#define M_TOK 8192

typedef unsigned short u16;
typedef __bf16 bf16x8 __attribute__((ext_vector_type(8)));
typedef float f32x4 __attribute__((ext_vector_type(4)));
typedef float f32x16 __attribute__((ext_vector_type(16)));

__device__ __forceinline__ u16 f2bf(float f) {
  union { float f; unsigned u; } v; v.f = f;
  unsigned u = v.u;
  return (u16)((u + 0x7fffu + ((u >> 16) & 1u)) >> 16);
}

__device__ __forceinline__ bf16x8 ld_frag(const u16* p) {
  bf16x8 r; __builtin_memcpy(&r, p, 16); return r;
}

__device__ __forceinline__ void gl_lds16(const u16* g, u16* l) {
  __builtin_amdgcn_global_load_lds(
      (const __attribute__((address_space(1))) void*)g,
      (__attribute__((address_space(3))) void*)l, 16, 0, 0);
}

__device__ __forceinline__ unsigned cvtpk(float lo, float hi_) {
  unsigned r;
  asm("v_cvt_pk_bf16_f32 %0, %1, %2" : "=v"(r) : "v"(lo), "v"(hi_));
  return r;
}

#define MFMA(a, b, c) __builtin_amdgcn_mfma_f32_16x16x32_bf16(a, b, c, 0, 0, 0)
#define MFMA32(a, b, c) __builtin_amdgcn_mfma_f32_32x32x16_bf16(a, b, c, 0, 0, 0)

__device__ __forceinline__ float vmax16(const f32x16& v) {
  float a = fmaxf(fmaxf(v[0], v[1]), fmaxf(v[2], v[3]));
  float b = fmaxf(fmaxf(v[4], v[5]), fmaxf(v[6], v[7]));
  float c = fmaxf(fmaxf(v[8], v[9]), fmaxf(v[10], v[11]));
  float d = fmaxf(fmaxf(v[12], v[13]), fmaxf(v[14], v[15]));
  return fmaxf(fmaxf(a, b), fmaxf(c, d));
}
__device__ __forceinline__ float vsum16(const f32x16& v) {
  float a = (v[0] + v[1]) + (v[2] + v[3]);
  float b = (v[4] + v[5]) + (v[6] + v[7]);
  float c = (v[8] + v[9]) + (v[10] + v[11]);
  float d = (v[12] + v[13]) + (v[14] + v[15]);
  return (a + b) + (c + d);
}

// ---------------- fp32 -> bf16 convert (optionally scale first scale_n) ----
__global__ __launch_bounds__(256) void k_f32_to_bf16(const float* __restrict__ s,
                                                     u16* __restrict__ d,
                                                     long scale_n) {
  long i = (long)(blockIdx.x * 256 + threadIdx.x) * 8;
  float sc = (i < scale_n) ? 0.08838834764831845f : 1.0f;
  float a[8];
  __builtin_memcpy(a, s + i, 32);
  u16 r[8];
#pragma unroll
  for (int j = 0; j < 8; ++j) r[j] = f2bf(a[j] * sc);
  __builtin_memcpy(d + i, r, 16);
}

// ---------------- 256x256 quad-buffered GEMM  C = A[M,K] * B[N,K]^T --------
// 8 waves (2Mx4N). BK=32, 4 LDS tile-buffers (128KB), prefetch 3 tiles ahead.
// 2-D XCD-rectangle swizzle: each XCD's 32 concurrent blocks cover a 4-row x
// 8-col tile rectangle (working set 12MB vs 34MB for column-strip order);
// A row-stripes are XCD-private so A is read once chip-wide.
template <int OUT_BF16>
__global__ __launch_bounds__(512, 2) void k_gemm256(const u16* __restrict__ A,
                                                    const u16* __restrict__ B,
                                                    void* __restrict__ C,
                                                    int M, int N, int K) {
  __shared__ __attribute__((aligned(16))) u16 As[4][8192];  // 4 x 16KB
  __shared__ __attribute__((aligned(16))) u16 Bs[4][8192];
  const int tid = threadIdx.x;
  const int lane = tid & 63;
  const int wid = tid >> 6;
  const int l15 = lane & 15, l4 = lane >> 4;
  const int wr = wid >> 2, wc = wid & 3;  // 2x4 waves -> 128x64 out each

  // M is always 8192 -> 32 row-tiles = 8 XCDs x 4-row stripes.
  const int xcd = blockIdx.x & 7;
  const int slot = blockIdx.x >> 3;
  const long tm = (long)(xcd * 4 + (slot & 3)) * 256;
  const long tn = (long)(slot >> 2) * 256;

  // T2 swizzle: stored chunk g = c ^ ((row>>1)&3); per-thread constant on
  // the read side since row = 16*frag + l15.
  const int cA = l4 ^ ((l15 >> 1) & 3);
  const int arow = wr * 128 + l15;
  const int brow = wc * 64 + l15;

  f32x4 acc[8][4] = {};
  bf16x8 af[4], bfr[4];

#define STG(dst, src, tbase, t_)                                          \
  do {                                                                    \
    _Pragma("unroll") for (int j = 0; j < 2; ++j) {                       \
      int p = tid + j * 512;                                              \
      int row = p >> 2, cc = p & 3;                                       \
      int g = cc ^ ((row >> 1) & 3);                                      \
      gl_lds16(src + (tbase + row) * (long)K + (long)(t_) * 32 + g * 8,   \
               (dst) + p * 8);                                            \
    }                                                                     \
  } while (0)

#define DSR_A(ptr, mh)                                                    \
  _Pragma("unroll") for (int m = 0; m < 4; ++m)                           \
      af[m] = ld_frag((ptr) + (arow + (mh) * 64 + m * 16) * 32 + cA * 8);
#define DSR_B(ptr)                                                        \
  _Pragma("unroll") for (int n = 0; n < 4; ++n)                           \
      bfr[n] = ld_frag((ptr) + (brow + n * 16) * 32 + cA * 8);
#define MM(mh)                                                            \
  _Pragma("unroll") for (int m = 0; m < 4; ++m)                           \
      _Pragma("unroll") for (int n = 0; n < 4; ++n)                       \
          acc[(mh) * 4 + m][n] = MFMA(af[m], bfr[n], acc[(mh) * 4 + m][n]);
#define LGKM0                                              \
  asm volatile("s_waitcnt lgkmcnt(0)" ::: "memory");       \
  __builtin_amdgcn_sched_barrier(0)

  const int NT = K >> 5;  // BK=32
  // prologue: stage tiles 0,1,2 (12 loads/thread); gate tile 0 (8 in flight)
  STG(&As[0][0], A, tm, 0); STG(&Bs[0][0], B, tn, 0);
  STG(&As[1][0], A, tm, 1); STG(&Bs[1][0], B, tn, 1);
  STG(&As[2][0], A, tm, 2); STG(&Bs[2][0], B, tn, 2);
  asm volatile("s_waitcnt vmcnt(8)" ::: "memory");
  __builtin_amdgcn_s_barrier();

  for (int t = 0; t < NT; ++t) {
    const u16* as_ = &As[t & 3][0];
    const u16* bs_ = &Bs[t & 3][0];
    u16* an_ = &As[(t + 3) & 3][0];
    u16* bn_ = &Bs[(t + 3) & 3][0];
    const bool st = (t + 3 < NT);

    // phase 0: A(mh0) + B reads, stage A(t+3)
    DSR_A(as_, 0);
    DSR_B(bs_);
    if (st) STG(an_, A, tm, t + 3);
    __builtin_amdgcn_s_barrier();
    LGKM0;
    __builtin_amdgcn_s_setprio(1); MM(0); __builtin_amdgcn_s_setprio(0);
    __builtin_amdgcn_s_barrier();

    // phase 1: A(mh1) reads (B reused), stage B(t+3)
    DSR_A(as_, 1);
    if (st) STG(bn_, B, tn, t + 3);
    __builtin_amdgcn_s_barrier();
    LGKM0;
    __builtin_amdgcn_s_setprio(1); MM(1); __builtin_amdgcn_s_setprio(0);
    // tile-boundary gate: drain tile t+1's 4 loads, keep t+2/t+3 in flight
    if (t + 3 < NT) {
      asm volatile("s_waitcnt vmcnt(8)" ::: "memory");
    } else if (t + 2 < NT) {
      asm volatile("s_waitcnt vmcnt(4)" ::: "memory");
    } else if (t + 1 < NT) {
      asm volatile("s_waitcnt vmcnt(0)" ::: "memory");
    }
    __builtin_amdgcn_s_barrier();
  }
#undef STG
#undef DSR_A
#undef DSR_B
#undef MM
#undef LGKM0

#pragma unroll
  for (int m = 0; m < 8; ++m)
#pragma unroll
    for (int n = 0; n < 4; ++n)
#pragma unroll
      for (int i = 0; i < 4; ++i) {
        long row = tm + wr * 128 + m * 16 + l4 * 4 + i;
        long col = tn + wc * 64 + n * 16 + l15;
        if (OUT_BF16)
          ((u16*)C)[row * N + col] = f2bf(acc[m][n][i]);
        else
          ((float*)C)[row * N + col] = acc[m][n][i];
      }
}

// ---------------- V transpose: qkv V-part [s,d] -> vt[b,kv][d][s] ----------
__global__ __launch_bounds__(256) void k_vtrans(const u16* __restrict__ qkv,
                                                u16* __restrict__ vt) {
  __shared__ u16 T[64][68];
  const int tid = threadIdx.x;
  const int st = blockIdx.x;
  const int dt = blockIdx.y;
  const int bh = blockIdx.z;
  const int b = bh >> 2, kvh = bh & 3;
  const long s0 = (long)st * 64, d0 = (long)dt * 64;
#pragma unroll
  for (int j = 0; j < 2; ++j) {
    int chunk = tid + j * 256;
    int row = chunk >> 3, c8 = chunk & 7;
    u16 tmp[8];
    __builtin_memcpy(tmp,
                     qkv + ((long)b * S_LEN + s0 + row) * QKV_W + 2560 +
                         kvh * DH + d0 + c8 * 8,
                     16);
    __builtin_memcpy(&T[row][c8 * 8], tmp, 16);
  }
  __syncthreads();
#pragma unroll
  for (int j = 0; j < 2; ++j) {
    int chunk = tid + j * 256;
    int drow = chunk >> 3, c8 = chunk & 7;
    u16 tmp[8];
#pragma unroll
    for (int e = 0; e < 8; ++e) tmp[e] = T[c8 * 8 + e][drow];
    __builtin_memcpy(vt + ((long)bh * DH + d0 + drow) * S_LEN + s0 + c8 * 8,
                     tmp, 16);
  }
}

// ---------------- flash attention, 8-wave 32x32 swapped-QK^T ---------------
__global__ __launch_bounds__(512, 2) void k_attn(const u16* __restrict__ qkv,
                                                 const u16* __restrict__ vt,
                                                 u16* __restrict__ ao) {
  __shared__ u16 Ks[2][64 * 128];
  __shared__ u16 Vs[2][128 * 64];
  const int tid = threadIdx.x;
  const int lane = tid & 63;
  const int wid = tid >> 6;
  const int l31 = lane & 31, hi = lane >> 5;
  const int qt = blockIdx.x & 7;
  const int hh = (blockIdx.x >> 3) & 3;
  const int bkv = blockIdx.x >> 5;
  const int b = bkv >> 2, kvh = bkv & 3;
  const int h = kvh * 4 + hh;
  const long rowbase = (long)b * S_LEN;
  const int q0 = qt * 256 + wid * 32;
  const long vbase = (long)bkv * DH * S_LEN;

  bf16x8 qf[8];
  {
    const u16* qrow = qkv + (rowbase + q0 + l31) * QKV_W + h * DH;
#pragma unroll
    for (int kk = 0; kk < 8; ++kk) qf[kk] = ld_frag(qrow + kk * 16 + hi * 8);
  }

  f32x16 o[4] = {};
  float m_run = -3.0e38f, l_run = 0.f;

#define STAGE(buf, tile)                                                      \
  do {                                                                        \
    long s0_ = (long)(tile) * 64;                                             \
    _Pragma("unroll") for (int j = 0; j < 2; ++j) {                           \
      int chunk = (wid * 2 + j) * 64 + lane;                                  \
      int row = chunk >> 4, cc = chunk & 15;                                  \
      gl_lds16(qkv + (rowbase + s0_ + row) * QKV_W + 2048 + kvh * DH +        \
                   ((cc ^ (row & 7)) * 8),                                    \
               &Ks[buf][chunk * 8]);                                          \
    }                                                                         \
    _Pragma("unroll") for (int j = 0; j < 2; ++j) {                           \
      int chunk = (wid * 2 + j) * 64 + lane;                                  \
      int row = chunk >> 3, cc = chunk & 7;                                   \
      gl_lds16(vt + vbase + (long)row * S_LEN + s0_ + ((cc ^ (row & 7)) * 8), \
               &Vs[buf][chunk * 8]);                                          \
    }                                                                         \
  } while (0)

  STAGE(0, 0);
  __syncthreads();

  int cur = 0;
  for (int kt = 0; kt < 32; ++kt) {
    if (kt + 1 < 32) STAGE(cur ^ 1, kt + 1);

    f32x16 p0 = {}, p1 = {};
    {
      const u16* ks = &Ks[cur][0];
      __builtin_amdgcn_s_setprio(1);
#pragma unroll
      for (int kk = 0; kk < 8; ++kk) {
        int ch0 = ((2 * kk + hi) ^ (l31 & 7));
        int ch1 = ((2 * kk + hi) ^ ((l31 + 32) & 7));
        bf16x8 kf0 = ld_frag(ks + l31 * 128 + ch0 * 8);
        bf16x8 kf1 = ld_frag(ks + (32 + l31) * 128 + ch1 * 8);
        p0 = MFMA32(kf0, qf[kk], p0);
        p1 = MFMA32(kf1, qf[kk], p1);
      }
      __builtin_amdgcn_s_setprio(0);
    }

    float mx = fmaxf(vmax16(p0), vmax16(p1));
    mx = fmaxf(mx, __shfl_xor(mx, 32, 64));
    bool need = (mx > m_run + 8.0f);
    if (__any(need)) {
      float nm = fmaxf(m_run, mx);
      float alpha = __expf(m_run - nm);
      m_run = nm;
      l_run *= alpha;
#pragma unroll
      for (int n2 = 0; n2 < 4; ++n2)
#pragma unroll
        for (int r = 0; r < 16; ++r) o[n2][r] *= alpha;
    }
#pragma unroll
    for (int r = 0; r < 16; ++r) {
      p0[r] = __expf(p0[r] - m_run);
      p1[r] = __expf(p1[r] - m_run);
    }
    float ts = vsum16(p0) + vsum16(p1);
    ts += __shfl_xor(ts, 32, 64);
    l_run += ts;

    {
      const u16* vs = &Vs[cur][0];
      __builtin_amdgcn_s_setprio(1);
#pragma unroll
      for (int ks_ = 0; ks_ < 4; ++ks_) {
        const f32x16& pp = (ks_ < 2) ? p0 : p1;
        const int bb = 8 * (ks_ & 1);
        unsigned A0 = cvtpk(pp[bb + 0], pp[bb + 1]);
        unsigned A1 = cvtpk(pp[bb + 2], pp[bb + 3]);
        unsigned B0 = cvtpk(pp[bb + 4], pp[bb + 5]);
        unsigned B1 = cvtpk(pp[bb + 6], pp[bb + 7]);
        asm volatile("v_permlane32_swap_b32 %0, %1" : "+v"(A0), "+v"(B0));
        asm volatile("v_permlane32_swap_b32 %0, %1" : "+v"(A1), "+v"(B1));
        union { unsigned u[4]; bf16x8 v; } pu;
        pu.u[0] = A0; pu.u[1] = A1; pu.u[2] = B0; pu.u[3] = B1;
#pragma unroll
        for (int n2 = 0; n2 < 4; ++n2) {
          int vr = n2 * 32 + l31;
          int ch = ((2 * ks_ + hi) ^ (vr & 7));
          bf16x8 vf = ld_frag(vs + vr * 64 + ch * 8);
          o[n2] = MFMA32(vf, pu.v, o[n2]);
        }
      }
      __builtin_amdgcn_s_setprio(0);
    }
    __syncthreads();
    cur ^= 1;
  }

  {
    float inv = 1.0f / l_run;
    u16* orow = ao + (rowbase + q0 + l31) * D_MODEL + h * DH;
#pragma unroll
    for (int n2 = 0; n2 < 4; ++n2)
#pragma unroll
      for (int g = 0; g < 4; ++g) {
        u16 tmp[4];
#pragma unroll
        for (int e = 0; e < 4; ++e) tmp[e] = f2bf(o[n2][g * 4 + e] * inv);
        __builtin_memcpy(orow + n2 * 32 + g * 8 + 4 * hi, tmp, 8);
      }
  }
#undef STAGE
}

// ---------------------------------------------------------------------------
extern "C" void kernel_launch(void* const* d_in, const int* in_sizes, int n_in,
                              void* d_out, int out_size, void* d_ws,
                              size_t ws_size, hipStream_t stream) {
  const float* x = (const float*)d_in[0];
  const float* wqkv = (const float*)d_in[2];
  const float* wo = (const float*)d_in[3];
  char* ws = (char*)d_ws;
  u16* xb = (u16*)(ws);                // 32MB (reused as ao later)
  u16* wqkvb = (u16*)(ws + 33554432);  // 12MB
  u16* wob = (u16*)(ws + 46137344);    // 8MB
  u16* qkv = (u16*)(ws + 54525952);    // 48MB
  u16* vt = (u16*)(ws + 104857600);    // 8MB
  u16* ao = xb;

  k_f32_to_bf16<<<8192, 256, 0, stream>>>(x, xb, 0);
  k_f32_to_bf16<<<3072, 256, 0, stream>>>(wqkv, wqkvb, 4194304L);
  k_f32_to_bf16<<<2048, 256, 0, stream>>>(wo, wob, 0);
  k_gemm256<1><<<384, 512, 0, stream>>>(xb, wqkvb, qkv, M_TOK, QKV_W, D_MODEL);
  k_vtrans<<<dim3(32, 2, 16), 256, 0, stream>>>(qkv, vt);
  k_attn<<<512, 512, 0, stream>>>(qkv, vt, ao);
  k_gemm256<0><<<256, 512, 0, stream>>>(ao, wob, d_out, M_TOK, D_MODEL,
                                        D_MODEL);
}